// Round 1
// baseline (51.924 us; speedup 1.0000x reference)
//
#include <hip/hip_runtime.h>
#include <hip/hip_bf16.h>

// SparseRescale: out[floor(y*0.7), floor(x*0.7)] = arr[y,x] for nonzero arr,
// numpy last-write-wins on collisions. Implemented as a GATHER: each output
// pixel owns a disjoint 1-2 x 1-2 window of source pixels (scale = 7/10
// exactly partitions the grid); iterate the window in row-major ascending
// order, last nonzero wins. Deterministic, no atomics, each input byte read
// exactly once.

#define ORIG_H 4320
#define ORIG_W 7680
#define NEW_H  3024
#define NEW_W  5376

__global__ void sparse_rescale_gather(const float* __restrict__ in,
                                      float* __restrict__ out) {
    const int ox = blockIdx.x * blockDim.x + threadIdx.x;   // 0..5375
    const int oy = blockIdx.y;                              // 0..3023

    // Source window: y in [ceil(10*oy/7), ceil(10*(oy+1)/7)), same for x.
    // y1 <= 4320 and x1 <= 7680 always, so no clamping needed.
    const int y0 = (10 * oy + 6) / 7;     // block-uniform -> scalar
    const int y1 = (10 * oy + 16) / 7;
    const int x0 = (10 * ox + 6) / 7;
    const int x1 = (10 * ox + 16) / 7;

    float v = 0.0f;
    #pragma unroll 2
    for (int y = y0; y < y1; ++y) {
        const float* __restrict__ row = in + (size_t)y * ORIG_W;
        #pragma unroll 2
        for (int x = x0; x < x1; ++x) {
            float a = row[x];
            if (a != 0.0f) v = a;        // last nonzero (row-major) wins
        }
    }
    out[(size_t)oy * NEW_W + ox] = v;
}

extern "C" void kernel_launch(void* const* d_in, const int* in_sizes, int n_in,
                              void* d_out, int out_size, void* d_ws, size_t ws_size,
                              hipStream_t stream) {
    const float* arr = (const float*)d_in[0];
    float* out = (float*)d_out;

    dim3 block(256, 1, 1);
    dim3 grid(NEW_W / 256, NEW_H, 1);    // 5376 = 21*256 exactly
    sparse_rescale_gather<<<grid, block, 0, stream>>>(arr, out);
}

// Round 2
// 33.907 us; speedup vs baseline: 1.5314x; 1.5314x over previous
//
#include <hip/hip_runtime.h>
#include <hip/hip_bf16.h>

// SparseRescale gather, LDS-staged:
//  - scale = 7/10 exactly: output pixel (oy,ox) owns disjoint source window
//    rows [ceil(10oy/7), ceil(10(oy+1)/7)) x cols [ceil(10ox/7), ceil(10(ox+1)/7))
//  - last nonzero in row-major order wins (numpy scatter semantics)
//  - block = one output row x 1792 output cols  <=>  1-2 input rows x 2560 cols
//    (1792*10/7 == 2560 exactly, so tiles partition both grids)
//  - stage input rows in LDS via coalesced float4; gather from LDS
//    (lane stride 1-2 floats -> <=2-way bank aliasing, free); coalesced stores.

#define ORIG_H 4320
#define ORIG_W 7680
#define NEW_H  3024
#define NEW_W  5376
#define TILE_OUT 1792   // 7*256
#define TILE_IN  2560   // TILE_OUT*10/7

__global__ __launch_bounds__(256)
void sparse_rescale_lds(const float* __restrict__ in, float* __restrict__ out) {
    __shared__ float sm[2][TILE_IN];     // 20 KB

    const int tid  = threadIdx.x;
    const int tile = blockIdx.x;         // 0..2
    const int oy   = blockIdx.y;         // 0..3023

    const int y0    = (10 * oy + 6) / 7;       // block-uniform
    const int y1    = (10 * oy + 16) / 7;      // y0+1 or y0+2
    const int nrows = y1 - y0;                 // 1 or 2
    const int xin0  = tile * TILE_IN;

    // Stage nrows input rows, coalesced float4 (2560 floats = 640 float4/row).
    for (int r = 0; r < nrows; ++r) {          // block-uniform trip count
        const float4* __restrict__ src =
            (const float4*)(in + (size_t)(y0 + r) * ORIG_W + xin0);
        float4* dst = (float4*)sm[r];
        #pragma unroll
        for (int i = 0; i < 3; ++i) {
            int idx = tid + 256 * i;
            if (idx < TILE_IN / 4) dst[idx] = src[idx];
        }
    }
    __syncthreads();

    const int oxbase = tile * TILE_OUT;
    const int rlast  = nrows - 1;              // 0 or 1; sm[rlast] == sm[0] if 1 row

    #pragma unroll
    for (int k = 0; k < 7; ++k) {
        const int oxl = tid + 256 * k;         // local output col, 0..1791
        const int x0  = (10 * oxl + 6) / 7;    // local input col window [x0, x1)
        const int x1  = (10 * oxl + 16) / 7;
        const int xw  = x1 - 1 - x0;           // 0 or 1

        // Row-major last-nonzero-wins over the <=2x2 window, branchless.
        // When window is 1 wide, b==a (duplicate read) leaves result unchanged;
        // when 1 tall, row1 duplicates row0 likewise.
        float a0 = sm[0][x0];
        float a1 = sm[0][x0 + xw];
        float b0 = sm[rlast][x0];
        float b1 = sm[rlast][x0 + xw];

        float v = 0.0f;
        if (a0 != 0.0f) v = a0;
        if (a1 != 0.0f) v = a1;
        if (b0 != 0.0f) v = b0;
        if (b1 != 0.0f) v = b1;

        out[(size_t)oy * NEW_W + oxbase + oxl] = v;
    }
}

extern "C" void kernel_launch(void* const* d_in, const int* in_sizes, int n_in,
                              void* d_out, int out_size, void* d_ws, size_t ws_size,
                              hipStream_t stream) {
    const float* arr = (const float*)d_in[0];
    float* out = (float*)d_out;

    dim3 block(256, 1, 1);
    dim3 grid(3, NEW_H, 1);                    // 3*1792 = 5376 output cols
    sparse_rescale_lds<<<grid, block, 0, stream>>>(arr, out);
}